// Round 14
// baseline (711.216 us; speedup 1.0000x reference)
//
#include <hip/hip_runtime.h>
#include <hip/hip_cooperative_groups.h>
#include <math.h>

namespace cg = cooperative_groups;

#define NND 6144
#define NED 12288
#define GRID 1024
static constexpr float EPS_BN = 1e-5f;

// ---------------- ws layout (float offsets) ----------------
#define HN_OFF    0         // Hn [N,32]
#define HE_OFF    196608    // he [N,2]
#define ST_OFF    208896    // [64]: sum0[16] sq0[16] | us5[5]
#define Y_OFF     208960    // YT [32,N]
#define T0_OFF    405568    // H [N,32]
#define ZT_OFF    602176    // ZtT [16,E]
#define ZC_OFF    798784    // Zc0 [E,16]
#define Z0_OFF    995392    // [E]
#define Z1_OFF    1007680   // [E]
#define U_OFF     1019968   // [E]
#define S_OFF     1032256   // [E]
#define PP_OFF    1044544   // head partials [32][N]

typedef float floatx4 __attribute__((ext_vector_type(4)));

__device__ __forceinline__ float4 ntload4(const float* p) {
  floatx4 v = __builtin_nontemporal_load(reinterpret_cast<const floatx4*>(p));
  return make_float4(v.x, v.y, v.z, v.w);
}
__device__ __forceinline__ float4 ld4(const float* p) {
  return *reinterpret_cast<const float4*>(p);
}
__device__ __forceinline__ void gll16(const float* g, float* l) {
  __builtin_amdgcn_global_load_lds(
      (const __attribute__((address_space(1))) unsigned int*)g,
      (__attribute__((address_space(3))) unsigned int*)l, 16, 0, 0);
}

struct Params {
  const float *X_n, *X_e, *A, *L1, *B1;
  const float *gW0, *gb0, *gW1, *gb1;
  const float *tW0, *tb0, *bng0, *bnb0;
  const float *tW1, *tb1, *bng1, *bnb1;
  const float *fc1W, *fc1b, *fc2W, *fc2b;
  float *ws;
  float *out;
};

// PHASE == 0: full pipeline with grid.sync (cooperative launch, 7 syncs).
// PHASE == k (1..8): fallback, one kernel per sync-interval.
template<int PHASE>
__global__ __launch_bounds__(256)
__attribute__((amdgpu_waves_per_eu(4, 4)))
void pipeline(Params p) {
  __shared__ float lds[10240];              // 40 KB pool -> 4 blocks/CU
  float* sst = &lds[10176];                 // 32-float scratch
  float* red = &lds[10208];                 // 20-float scratch

  const int tid  = threadIdx.x;
  const int lane = tid & 63;
  const int w    = tid >> 6;
  const int blk  = blockIdx.x;
  const int gtid = blk * 256 + tid;
  constexpr bool ALL = (PHASE == 0);

  float* Hn = p.ws + HN_OFF;
  float* he = p.ws + HE_OFF;
  float* st = p.ws + ST_OFF;
  float* Y  = p.ws + Y_OFF;
  float* T0 = p.ws + T0_OFF;
  float* ZT = p.ws + ZT_OFF;
  float* ZC = p.ws + ZC_OFF;
  float* Z0 = p.ws + Z0_OFF;
  float* Z1 = p.ws + Z1_OFF;
  float* u  = p.ws + U_OFF;
  float* s  = p.ws + S_OFF;
  float* pp = p.ws + PP_OFF;

  // gemm32: out = relu(A@Y^T + b). 6 rows/block; wave = 3 rows x 16 cols.
  // LDS: Y 32x256 (lds[0..8191]) + A 6x256 (lds[8192..9727]).
  auto gemm32 = [&](const float* bias, float* outp) {
    const int rg = w >> 1, cg_ = w & 1;
    const int r0 = blk * 6;
    const int c0 = cg_ * 16;
    float acc[3][16];
    #pragma unroll
    for (int r = 0; r < 3; ++r)
      #pragma unroll
      for (int c = 0; c < 16; ++c) acc[r][c] = 0.f;

    for (int kb = 0; kb < NND; kb += 256) {
      #pragma unroll
      for (int i = 0; i < 8; ++i) {
        const int yr = w * 8 + i;
        gll16(Y + (size_t)yr * NND + kb + lane * 4, &lds[yr * 256]);
      }
      #pragma unroll
      for (int i = 0; i < 2; ++i) {
        const int ar = w * 2 + i;
        if (ar < 6)
          gll16(p.A + (size_t)(r0 + ar) * NND + kb + lane * 4, &lds[8192 + ar * 256]);
      }
      __syncthreads();
      float4 av[3];
      #pragma unroll
      for (int r = 0; r < 3; ++r)
        av[r] = ld4(&lds[8192 + (rg * 3 + r) * 256 + lane * 4]);
      #pragma unroll
      for (int c = 0; c < 16; ++c) {
        const float4 y = ld4(&lds[(c0 + c) * 256 + lane * 4]);
        #pragma unroll
        for (int r = 0; r < 3; ++r) {
          acc[r][c] = fmaf(av[r].x, y.x, acc[r][c]);
          acc[r][c] = fmaf(av[r].y, y.y, acc[r][c]);
          acc[r][c] = fmaf(av[r].z, y.z, acc[r][c]);
          acc[r][c] = fmaf(av[r].w, y.w, acc[r][c]);
        }
      }
      __syncthreads();
    }
    #pragma unroll
    for (int r = 0; r < 3; ++r) {
      float wv[16];
      #pragma unroll
      for (int c = 0; c < 16; ++c) {
        float t = acc[r][c] + __shfl_xor(acc[r][c], 32, 64);
        wv[c] = t + __shfl_xor(t, 16, 64);
      }
      #pragma unroll
      for (int b = 3; b >= 0; --b) {
        const int m = 1 << b;
        const bool hi = (lane & m) != 0;
        #pragma unroll
        for (int i = 0; i < (1 << b); ++i) {
          float x = wv[i], yv = wv[i + (1 << b)];
          float send = hi ? x : yv;
          float recv = __shfl_xor(send, m, 64);
          wv[i] = (hi ? yv : x) + recv;
        }
      }
      if (lane < 16) {
        float v = fmaxf(wv[0] + bias[c0 + lane], 0.f);
        outp[(size_t)(r0 + rg * 3 + r) * 32 + c0 + lane] = v;
      }
    }
  };

  // ==== Interval 1: zero stats; Y0T = X_n@gW0^T; ZtT = X_e@tW0^T + tb0 ====
  if constexpr (ALL || PHASE == 1) {
    if (blk == 0 && tid < 64) st[tid] = 0.f;
    if (gtid < NND) {
      const int m = gtid;
      float x[32];
      #pragma unroll
      for (int k = 0; k < 32; k += 4) {
        float4 v = ld4(p.X_n + (size_t)m * 32 + k);
        x[k] = v.x; x[k+1] = v.y; x[k+2] = v.z; x[k+3] = v.w;
      }
      #pragma unroll
      for (int oc = 0; oc < 32; ++oc) {
        float acc = 0.f;
        #pragma unroll
        for (int k = 0; k < 32; ++k) acc = fmaf(x[k], p.gW0[oc * 32 + k], acc);
        Y[(size_t)oc * NND + m] = acc;
      }
    } else if (gtid < NND + NED) {
      const int e = gtid - NND;
      float x[16];
      #pragma unroll
      for (int k = 0; k < 16; k += 4) {
        float4 v = ld4(p.X_e + (size_t)e * 16 + k);
        x[k] = v.x; x[k+1] = v.y; x[k+2] = v.z; x[k+3] = v.w;
      }
      #pragma unroll
      for (int oc = 0; oc < 16; ++oc) {
        float acc = p.tb0[oc];
        #pragma unroll
        for (int k = 0; k < 16; ++k) acc = fmaf(x[k], p.tW0[oc * 16 + k], acc);
        ZT[(size_t)oc * NED + e] = acc;
      }
    }
  }
  if constexpr (ALL) cg::this_grid().sync();

  // ==== Interval 2: P2 (H = relu(A@Y0+gb0)) then P5 (Zc0 = L1@Zt + stats) ====
  if constexpr (ALL || PHASE == 2) {
    gemm32(p.gb0, T0);

    // P5: 12 rows/block; wave = 3 rows x 16 cols.
    // LDS: Zt 16x256 (lds[0..4095]) + L1 12x256 (lds[4096..7167]).
    const int r0 = blk * 12;
    float acc[3][16];
    #pragma unroll
    for (int r = 0; r < 3; ++r)
      #pragma unroll
      for (int c = 0; c < 16; ++c) acc[r][c] = 0.f;

    for (int kb = 0; kb < NED; kb += 256) {
      #pragma unroll
      for (int i = 0; i < 4; ++i) {
        const int yr = w * 4 + i;
        gll16(ZT + (size_t)yr * NED + kb + lane * 4, &lds[yr * 256]);
      }
      #pragma unroll
      for (int i = 0; i < 3; ++i) {
        const int ar = w * 3 + i;
        gll16(p.L1 + (size_t)(r0 + ar) * NED + kb + lane * 4, &lds[4096 + ar * 256]);
      }
      __syncthreads();
      float4 av[3];
      #pragma unroll
      for (int r = 0; r < 3; ++r)
        av[r] = ld4(&lds[4096 + (w * 3 + r) * 256 + lane * 4]);
      #pragma unroll
      for (int c = 0; c < 16; ++c) {
        const float4 y = ld4(&lds[c * 256 + lane * 4]);
        #pragma unroll
        for (int r = 0; r < 3; ++r) {
          acc[r][c] = fmaf(av[r].x, y.x, acc[r][c]);
          acc[r][c] = fmaf(av[r].y, y.y, acc[r][c]);
          acc[r][c] = fmaf(av[r].z, y.z, acc[r][c]);
          acc[r][c] = fmaf(av[r].w, y.w, acc[r][c]);
        }
      }
      __syncthreads();
    }
    float stS = 0.f, stQ = 0.f;
    #pragma unroll
    for (int r = 0; r < 3; ++r) {
      float wv[16];
      #pragma unroll
      for (int c = 0; c < 16; ++c) {
        float t = acc[r][c] + __shfl_xor(acc[r][c], 32, 64);
        wv[c] = t + __shfl_xor(t, 16, 64);
      }
      #pragma unroll
      for (int b = 3; b >= 0; --b) {
        const int m = 1 << b;
        const bool hi = (lane & m) != 0;
        #pragma unroll
        for (int i = 0; i < (1 << b); ++i) {
          float x = wv[i], yv = wv[i + (1 << b)];
          float send = hi ? x : yv;
          float recv = __shfl_xor(send, m, 64);
          wv[i] = (hi ? yv : x) + recv;
        }
      }
      if (lane < 16) {
        const float v = wv[0];
        ZC[(size_t)(r0 + w * 3 + r) * 16 + lane] = v;
        stS += v; stQ += v * v;
      }
    }
    if (tid < 32) sst[tid] = 0.f;
    __syncthreads();
    if (lane < 16) {
      atomicAdd(&sst[lane], stS);
      atomicAdd(&sst[16 + lane], stQ);
    }
    __syncthreads();
    if (tid < 32) atomicAdd(st + tid, sst[tid]);
  }
  if constexpr (ALL) cg::this_grid().sync();

  // ==== Interval 3: P3 (Y1T = H@gW1^T) || P6 (Z0 from ZC + stats) ====
  if constexpr (ALL || PHASE == 3) {
    if (gtid < NND) {
      const int m = gtid;
      float x[32];
      #pragma unroll
      for (int k = 0; k < 32; k += 4) {
        float4 v = ld4(T0 + (size_t)m * 32 + k);
        x[k] = v.x; x[k+1] = v.y; x[k+2] = v.z; x[k+3] = v.w;
      }
      #pragma unroll
      for (int oc = 0; oc < 32; ++oc) {
        float acc = 0.f;
        #pragma unroll
        for (int k = 0; k < 32; ++k) acc = fmaf(x[k], p.gW1[oc * 32 + k], acc);
        Y[(size_t)oc * NND + m] = acc;
      }
    } else if (gtid < NND + NED) {
      const int e = gtid - NND;
      const float invE = 1.f / (float)NED;
      float best = -3.4e38f;
      #pragma unroll
      for (int c = 0; c < 16; ++c) {
        float m = st[c] * invE;
        float var = st[16 + c] * invE - m * m;
        float sc = p.bng0[c] * rsqrtf(var + EPS_BN);
        float sh = p.bnb0[c] - m * sc;
        best = fmaxf(best, fmaf(ZC[(size_t)e * 16 + c], sc, sh));
      }
      Z0[e] = fmaxf(best, 0.f);
    }
  }
  if constexpr (ALL) cg::this_grid().sync();

  // ==== Interval 4: P4 (Hn = relu(A@Y1+gb1)) then P7 (u,s = L1@[Z0,1], st5) ====
  if constexpr (ALL || PHASE == 4) {
    gemm32(p.gb1, Hn);

    // P7: 12 rows/block, 3 rows/wave, REV order (L3 tail reuse), depth-1 prefetch.
    const int rb = GRID - 1 - blk;
    const int r0 = rb * 12 + w * 3;
    const float* mp[3];
    #pragma unroll
    for (int r = 0; r < 3; ++r) mp[r] = p.L1 + (size_t)(r0 + r) * NED;
    float ua[3] = {0,0,0}, sa[3] = {0,0,0};
    float4 a[3], an[3];
    #pragma unroll
    for (int r = 0; r < 3; ++r) a[r] = ntload4(mp[r] + lane * 4);
    float4 z = ld4(Z0 + lane * 4), zn;
    for (int kb = 0; kb < NED; kb += 256) {
      const int k = kb + lane * 4;
      const bool more = (kb + 256) < NED;
      if (more) {
        #pragma unroll
        for (int r = 0; r < 3; ++r) an[r] = ntload4(mp[r] + k + 256);
        zn = ld4(Z0 + k + 256);
      }
      #pragma unroll
      for (int r = 0; r < 3; ++r) {
        ua[r] += a[r].x*z.x + a[r].y*z.y + a[r].z*z.z + a[r].w*z.w;
        sa[r] += a[r].x + a[r].y + a[r].z + a[r].w;
      }
      if (more) {
        #pragma unroll
        for (int r = 0; r < 3; ++r) a[r] = an[r];
        z = zn;
      }
    }
    #pragma unroll
    for (int r = 0; r < 3; ++r)
      #pragma unroll
      for (int m = 1; m < 64; m <<= 1) {
        ua[r] += __shfl_xor(ua[r], m, 64);
        sa[r] += __shfl_xor(sa[r], m, 64);
      }
    if (lane == 0) {
      float s1 = 0.f, s2 = 0.f, s3 = 0.f, s4 = 0.f, s5 = 0.f;
      #pragma unroll
      for (int r = 0; r < 3; ++r) {
        u[r0 + r] = ua[r]; s[r0 + r] = sa[r];
        s1 += ua[r]; s2 += sa[r];
        s3 += ua[r] * ua[r]; s4 += sa[r] * sa[r]; s5 += ua[r] * sa[r];
      }
      red[w * 5 + 0] = s1; red[w * 5 + 1] = s2; red[w * 5 + 2] = s3;
      red[w * 5 + 3] = s4; red[w * 5 + 4] = s5;
    }
    __syncthreads();
    if (tid < 5)
      atomicAdd(st + 32 + tid, red[tid] + red[5 + tid] + red[10 + tid] + red[15 + tid]);
  }
  if constexpr (ALL) cg::this_grid().sync();

  // ==== Interval 5: P8 (Z1 from u,s via collapsed BN) ====
  if constexpr (ALL || PHASE == 5) {
    if (gtid < NED) {
      const int e = gtid;
      const float invE = 1.f / (float)NED;
      const float Su = st[32], Ss = st[33], Suu = st[34], Sss = st[35], Sus = st[36];
      const float uu = u[e], ssv = s[e];
      float best = -3.4e38f;
      #pragma unroll
      for (int c = 0; c < 16; ++c) {
        const float wc = p.tW1[c], bc = p.tb1[c];
        const float mean = (wc * Su + bc * Ss) * invE;
        const float ex2 = (wc * wc * Suu + 2.f * wc * bc * Sus + bc * bc * Sss) * invE;
        const float var = ex2 - mean * mean;
        const float sc = p.bng1[c] * rsqrtf(var + EPS_BN);
        const float sh = p.bnb1[c] - mean * sc;
        best = fmaxf(best, fmaf(wc * uu + bc * ssv, sc, sh));
      }
      Z1[e] = fmaxf(best, 0.f);
    }
  }
  if constexpr (ALL) cg::this_grid().sync();

  // ==== Interval 6: P9 (he = B1 @ [Z0 Z1]); 12 rows/block, first 512 blocks ====
  if constexpr (ALL || PHASE == 6) {
    const int r0 = blk * 12 + w * 3;
    if (r0 < NND) {
      const float* mp[3];
      #pragma unroll
      for (int r = 0; r < 3; ++r) mp[r] = p.B1 + (size_t)(r0 + r) * NED;
      float uu[3] = {0,0,0}, vv[3] = {0,0,0};
      float4 a[3], an[3];
      #pragma unroll
      for (int r = 0; r < 3; ++r) a[r] = ntload4(mp[r] + lane * 4);
      float4 z = ld4(Z0 + lane * 4), y = ld4(Z1 + lane * 4), zn, yn;
      for (int kb = 0; kb < NED; kb += 256) {
        const int k = kb + lane * 4;
        const bool more = (kb + 256) < NED;
        if (more) {
          #pragma unroll
          for (int r = 0; r < 3; ++r) an[r] = ntload4(mp[r] + k + 256);
          zn = ld4(Z0 + k + 256); yn = ld4(Z1 + k + 256);
        }
        #pragma unroll
        for (int r = 0; r < 3; ++r) {
          uu[r] += a[r].x*z.x + a[r].y*z.y + a[r].z*z.z + a[r].w*z.w;
          vv[r] += a[r].x*y.x + a[r].y*y.y + a[r].z*y.z + a[r].w*y.w;
        }
        if (more) {
          #pragma unroll
          for (int r = 0; r < 3; ++r) a[r] = an[r];
          z = zn; y = yn;
        }
      }
      #pragma unroll
      for (int r = 0; r < 3; ++r)
        #pragma unroll
        for (int m = 1; m < 64; m <<= 1) {
          uu[r] += __shfl_xor(uu[r], m, 64);
          vv[r] += __shfl_xor(vv[r], m, 64);
        }
      if (lane == 0) {
        #pragma unroll
        for (int r = 0; r < 3; ++r) {
          he[(r0 + r) * 2]     = uu[r];
          he[(r0 + r) * 2 + 1] = vv[r];
        }
      }
    }
  }
  if constexpr (ALL) cg::this_grid().sync();

  // ==== Interval 7: P10 head partials — 1 row/thread, NO spills.
  // 768 active blocks: nb = blk%24 (256-row band), jb = blk/24 (32 chunks x 384 j).
  // j coverage: 32 x 384 = 12288 = 2N.  (R13 bug: was 64 j -> 1/6 coverage.)
  if constexpr (ALL || PHASE == 7) {
    if (blk < 768) {
      const int nb = blk % 24, jb = blk / 24;
      const int n = nb * 256 + tid;
      float h[34];
      #pragma unroll
      for (int k = 0; k < 32; k += 4) {
        float4 v = ld4(Hn + (size_t)n * 32 + k);
        h[k] = v.x; h[k+1] = v.y; h[k+2] = v.z; h[k+3] = v.w;
      }
      float2 e2 = *reinterpret_cast<const float2*>(he + n * 2);
      h[32] = e2.x; h[33] = e2.y;
      float acc = 0.f;
      const int j0 = jb * 384;
      for (int j = j0; j < j0 + 384; ++j) {
        const float* wp = p.fc1W + (size_t)j * 34;
        float s0 = p.fc1b[j];
        #pragma unroll
        for (int k = 0; k < 34; ++k) s0 = fmaf(h[k], wp[k], s0);
        acc = fmaf(fmaxf(s0, 0.f), p.fc2W[j], acc);
      }
      pp[(size_t)jb * NND + n] = acc;
    }
  }
  if constexpr (ALL) cg::this_grid().sync();

  // ==== Interval 8: P11 final reduce + sigmoid ====
  if constexpr (ALL || PHASE == 8) {
    if (gtid < NND) {
      float acc = 0.f;
      #pragma unroll
      for (int j = 0; j < 32; ++j) acc += pp[(size_t)j * NND + gtid];
      p.out[gtid] = 1.f / (1.f + expf(-(acc + p.fc2b[0])));
    }
  }
}

extern "C" void kernel_launch(void* const* d_in, const int* in_sizes, int n_in,
                              void* d_out, int out_size, void* d_ws, size_t ws_size,
                              hipStream_t stream) {
  Params p;
  p.X_n  = (const float*)d_in[0];
  p.X_e  = (const float*)d_in[1];
  p.A    = (const float*)d_in[2];
  p.L1   = (const float*)d_in[3];
  p.B1   = (const float*)d_in[4];
  p.gW0  = (const float*)d_in[5];
  p.gb0  = (const float*)d_in[6];
  p.gW1  = (const float*)d_in[7];
  p.gb1  = (const float*)d_in[8];
  p.tW0  = (const float*)d_in[9];
  p.tb0  = (const float*)d_in[10];
  p.bng0 = (const float*)d_in[11];
  p.bnb0 = (const float*)d_in[12];
  p.tW1  = (const float*)d_in[13];
  p.tb1  = (const float*)d_in[14];
  p.bng1 = (const float*)d_in[15];
  p.bnb1 = (const float*)d_in[16];
  p.fc1W = (const float*)d_in[17];
  p.fc1b = (const float*)d_in[18];
  p.fc2W = (const float*)d_in[19];
  p.fc2b = (const float*)d_in[20];
  p.ws   = (float*)d_ws;
  p.out  = (float*)d_out;

  int maxBlk = 0;
  hipError_t oe = hipOccupancyMaxActiveBlocksPerMultiprocessor(
      &maxBlk, pipeline<0>, 256, 0);
  bool coop_ok = (oe == hipSuccess) && (maxBlk >= 4);

  if (coop_ok) {
    void* kargs[] = { &p };
    hipError_t le = hipLaunchCooperativeKernel(
        (const void*)&pipeline<0>, dim3(GRID), dim3(256), kargs, 0, stream);
    if (le == hipSuccess) return;
  }

  // Fallback: identical intervals as separate kernels.
  pipeline<1><<<GRID, 256, 0, stream>>>(p);
  pipeline<2><<<GRID, 256, 0, stream>>>(p);
  pipeline<3><<<GRID, 256, 0, stream>>>(p);
  pipeline<4><<<GRID, 256, 0, stream>>>(p);
  pipeline<5><<<GRID, 256, 0, stream>>>(p);
  pipeline<6><<<GRID, 256, 0, stream>>>(p);
  pipeline<7><<<GRID, 256, 0, stream>>>(p);
  pipeline<8><<<GRID, 256, 0, stream>>>(p);
}

// Round 15
// 647.333 us; speedup vs baseline: 1.0987x; 1.0987x over previous
//
#include <hip/hip_runtime.h>
#include <math.h>

#define NND 6144
#define NED 12288
static constexpr float EPS_BN = 1e-5f;

// ---------------- ws layout (float offsets) ----------------
#define HN_OFF    0         // Hn [N,32]
#define HE_OFF    196608    // he [N,2]
#define ST_OFF    208896    // [64]: sum0[16] sq0[16] | us5[5]
#define Y_OFF     208960    // YT [32,N]
#define T0_OFF    405568    // H [N,32]
#define ZT_OFF    602176    // ZtT [16,E]
#define ZC_OFF    798784    // Zc0 [E,16]
#define Z0_OFF    995392    // [E]
#define Z1_OFF    1007680   // [E]
#define U_OFF     1019968   // [E]
#define S_OFF     1032256   // [E]
#define PP_OFF    1044544   // head partials [64][N]

typedef float floatx4 __attribute__((ext_vector_type(4)));

__device__ __forceinline__ float4 ntload4(const float* p) {
  floatx4 v = __builtin_nontemporal_load(reinterpret_cast<const floatx4*>(p));
  return make_float4(v.x, v.y, v.z, v.w);
}
__device__ __forceinline__ float4 ld4(const float* p) {
  return *reinterpret_cast<const float4*>(p);
}
__device__ __forceinline__ void gll16(const float* g, float* l) {
  __builtin_amdgcn_global_load_lds(
      (const __attribute__((address_space(1))) unsigned int*)g,
      (__attribute__((address_space(3))) unsigned int*)l, 16, 0, 0);
}

// ==== K1: zero stats; Y0T = X_n@gW0^T; ZtT = X_e@tW0^T + tb0. 72 blocks. ====
__global__ __launch_bounds__(256)
void k1_prep(const float* __restrict__ X_n, const float* __restrict__ X_e,
             const float* __restrict__ gW0, const float* __restrict__ tW0,
             const float* __restrict__ tb0, float* __restrict__ Y,
             float* __restrict__ ZT, float* __restrict__ st) {
  const int gtid = blockIdx.x * 256 + threadIdx.x;
  if (blockIdx.x == 0 && threadIdx.x < 64) st[threadIdx.x] = 0.f;
  if (gtid < NND) {
    const int m = gtid;
    float x[32];
    #pragma unroll
    for (int k = 0; k < 32; k += 4) {
      float4 v = ld4(X_n + (size_t)m * 32 + k);
      x[k] = v.x; x[k+1] = v.y; x[k+2] = v.z; x[k+3] = v.w;
    }
    #pragma unroll
    for (int oc = 0; oc < 32; ++oc) {
      float acc = 0.f;
      #pragma unroll
      for (int k = 0; k < 32; ++k) acc = fmaf(x[k], gW0[oc * 32 + k], acc);
      Y[(size_t)oc * NND + m] = acc;
    }
  } else if (gtid < NND + NED) {
    const int e = gtid - NND;
    float x[16];
    #pragma unroll
    for (int k = 0; k < 16; k += 4) {
      float4 v = ld4(X_e + (size_t)e * 16 + k);
      x[k] = v.x; x[k+1] = v.y; x[k+2] = v.z; x[k+3] = v.w;
    }
    #pragma unroll
    for (int oc = 0; oc < 16; ++oc) {
      float acc = tb0[oc];
      #pragma unroll
      for (int k = 0; k < 16; ++k) acc = fmaf(x[k], tW0[oc * 16 + k], acc);
      ZT[(size_t)oc * NED + e] = acc;
    }
  }
}

// ==== K2/K4: out = relu(A@Y^T + b). 1024 blocks x 6 rows; 4 blocks/CU. ====
__global__ __launch_bounds__(256, 4)
void k2_gemm32(const float* __restrict__ A, const float* __restrict__ Y,
               const float* __restrict__ bias, float* __restrict__ outp) {
  __shared__ float lds[9728];   // Y 32x256 (8192) + A 6x256 (1536)
  const int tid = threadIdx.x, lane = tid & 63, w = tid >> 6;
  const int rg = w >> 1, cg_ = w & 1;
  const int r0 = blockIdx.x * 6;
  const int c0 = cg_ * 16;
  float acc[3][16];
  #pragma unroll
  for (int r = 0; r < 3; ++r)
    #pragma unroll
    for (int c = 0; c < 16; ++c) acc[r][c] = 0.f;

  for (int kb = 0; kb < NND; kb += 256) {
    #pragma unroll
    for (int i = 0; i < 8; ++i) {
      const int yr = w * 8 + i;
      gll16(Y + (size_t)yr * NND + kb + lane * 4, &lds[yr * 256]);
    }
    #pragma unroll
    for (int i = 0; i < 2; ++i) {
      const int ar = w * 2 + i;
      if (ar < 6)
        gll16(A + (size_t)(r0 + ar) * NND + kb + lane * 4, &lds[8192 + ar * 256]);
    }
    __syncthreads();
    float4 av[3];
    #pragma unroll
    for (int r = 0; r < 3; ++r)
      av[r] = ld4(&lds[8192 + (rg * 3 + r) * 256 + lane * 4]);
    #pragma unroll
    for (int c = 0; c < 16; ++c) {
      const float4 y = ld4(&lds[(c0 + c) * 256 + lane * 4]);
      #pragma unroll
      for (int r = 0; r < 3; ++r) {
        acc[r][c] = fmaf(av[r].x, y.x, acc[r][c]);
        acc[r][c] = fmaf(av[r].y, y.y, acc[r][c]);
        acc[r][c] = fmaf(av[r].z, y.z, acc[r][c]);
        acc[r][c] = fmaf(av[r].w, y.w, acc[r][c]);
      }
    }
    __syncthreads();
  }
  #pragma unroll
  for (int r = 0; r < 3; ++r) {
    float wv[16];
    #pragma unroll
    for (int c = 0; c < 16; ++c) {
      float t = acc[r][c] + __shfl_xor(acc[r][c], 32, 64);
      wv[c] = t + __shfl_xor(t, 16, 64);
    }
    #pragma unroll
    for (int b = 3; b >= 0; --b) {
      const int m = 1 << b;
      const bool hi = (lane & m) != 0;
      #pragma unroll
      for (int i = 0; i < (1 << b); ++i) {
        float x = wv[i], yv = wv[i + (1 << b)];
        float send = hi ? x : yv;
        float recv = __shfl_xor(send, m, 64);
        wv[i] = (hi ? yv : x) + recv;
      }
    }
    if (lane < 16) {
      float v = fmaxf(wv[0] + bias[c0 + lane], 0.f);
      outp[(size_t)(r0 + rg * 3 + r) * 32 + c0 + lane] = v;
    }
  }
}

// ==== K3: Y1T = H@gW1^T. 24 blocks. ====
__global__ __launch_bounds__(256)
void k3_small(const float* __restrict__ T0, const float* __restrict__ gW1,
              float* __restrict__ Y) {
  const int m = blockIdx.x * 256 + threadIdx.x;
  float x[32];
  #pragma unroll
  for (int k = 0; k < 32; k += 4) {
    float4 v = ld4(T0 + (size_t)m * 32 + k);
    x[k] = v.x; x[k+1] = v.y; x[k+2] = v.z; x[k+3] = v.w;
  }
  #pragma unroll
  for (int oc = 0; oc < 32; ++oc) {
    float acc = 0.f;
    #pragma unroll
    for (int k = 0; k < 32; ++k) acc = fmaf(x[k], gW1[oc * 32 + k], acc);
    Y[(size_t)oc * NND + m] = acc;
  }
}

// ==== K5: Zc0 = L1@Zt^T + fused BN stats. 1024 blocks x 12 rows; 4/CU. ====
__global__ __launch_bounds__(256, 4)
void k5_l1gemm(const float* __restrict__ L1, const float* __restrict__ ZT,
               float* __restrict__ ZC, float* __restrict__ st) {
  __shared__ float lds[7168];   // Zt 16x256 (4096) + L1 12x256 (3072)
  __shared__ float sst[32];
  const int tid = threadIdx.x, lane = tid & 63, w = tid >> 6;
  const int r0 = blockIdx.x * 12;
  float acc[3][16];
  #pragma unroll
  for (int r = 0; r < 3; ++r)
    #pragma unroll
    for (int c = 0; c < 16; ++c) acc[r][c] = 0.f;

  for (int kb = 0; kb < NED; kb += 256) {
    #pragma unroll
    for (int i = 0; i < 4; ++i) {
      const int yr = w * 4 + i;
      gll16(ZT + (size_t)yr * NED + kb + lane * 4, &lds[yr * 256]);
    }
    #pragma unroll
    for (int i = 0; i < 3; ++i) {
      const int ar = w * 3 + i;
      gll16(L1 + (size_t)(r0 + ar) * NED + kb + lane * 4, &lds[4096 + ar * 256]);
    }
    __syncthreads();
    float4 av[3];
    #pragma unroll
    for (int r = 0; r < 3; ++r)
      av[r] = ld4(&lds[4096 + (w * 3 + r) * 256 + lane * 4]);
    #pragma unroll
    for (int c = 0; c < 16; ++c) {
      const float4 y = ld4(&lds[c * 256 + lane * 4]);
      #pragma unroll
      for (int r = 0; r < 3; ++r) {
        acc[r][c] = fmaf(av[r].x, y.x, acc[r][c]);
        acc[r][c] = fmaf(av[r].y, y.y, acc[r][c]);
        acc[r][c] = fmaf(av[r].z, y.z, acc[r][c]);
        acc[r][c] = fmaf(av[r].w, y.w, acc[r][c]);
      }
    }
    __syncthreads();
  }
  float stS = 0.f, stQ = 0.f;
  #pragma unroll
  for (int r = 0; r < 3; ++r) {
    float wv[16];
    #pragma unroll
    for (int c = 0; c < 16; ++c) {
      float t = acc[r][c] + __shfl_xor(acc[r][c], 32, 64);
      wv[c] = t + __shfl_xor(t, 16, 64);
    }
    #pragma unroll
    for (int b = 3; b >= 0; --b) {
      const int m = 1 << b;
      const bool hi = (lane & m) != 0;
      #pragma unroll
      for (int i = 0; i < (1 << b); ++i) {
        float x = wv[i], yv = wv[i + (1 << b)];
        float send = hi ? x : yv;
        float recv = __shfl_xor(send, m, 64);
        wv[i] = (hi ? yv : x) + recv;
      }
    }
    if (lane < 16) {
      const float v = wv[0];
      ZC[(size_t)(r0 + w * 3 + r) * 16 + lane] = v;
      stS += v; stQ += v * v;
    }
  }
  if (tid < 32) sst[tid] = 0.f;
  __syncthreads();
  if (lane < 16) {
    atomicAdd(&sst[lane], stS);
    atomicAdd(&sst[16 + lane], stQ);
  }
  __syncthreads();
  if (tid < 32) atomicAdd(st + tid, sst[tid]);
}

// ==== K6: Z0 = relu(max_c BN(Zc0)). 48 blocks. ====
__global__ __launch_bounds__(256)
void k6_bnmax(const float* __restrict__ ZC, const float* __restrict__ st,
              const float* __restrict__ g, const float* __restrict__ beta,
              float* __restrict__ Z0) {
  const int e = blockIdx.x * 256 + threadIdx.x;
  const float invE = 1.f / (float)NED;
  float best = -3.4e38f;
  #pragma unroll
  for (int c = 0; c < 16; ++c) {
    float m = st[c] * invE;
    float var = st[16 + c] * invE - m * m;
    float sc = g[c] * rsqrtf(var + EPS_BN);
    float sh = beta[c] - m * sc;
    best = fmaxf(best, fmaf(ZC[(size_t)e * 16 + c], sc, sh));
  }
  Z0[e] = fmaxf(best, 0.f);
}

// ==== K7: u = L1@Z0, s = L1@1, fused st5. 1024 blocks x 12 rows, REV. ====
__global__ __launch_bounds__(256, 4)
void k7_uspass(const float* __restrict__ L1, const float* __restrict__ Z0,
               float* __restrict__ u, float* __restrict__ s,
               float* __restrict__ st5) {
  __shared__ float red[20];
  const int tid = threadIdx.x, lane = tid & 63, w = tid >> 6;
  const int rb = gridDim.x - 1 - blockIdx.x;
  const int r0 = rb * 12 + w * 3;
  const float* mp[3];
  #pragma unroll
  for (int r = 0; r < 3; ++r) mp[r] = L1 + (size_t)(r0 + r) * NED;
  float ua[3] = {0,0,0}, sa[3] = {0,0,0};
  float4 a[3], an[3];
  #pragma unroll
  for (int r = 0; r < 3; ++r) a[r] = ntload4(mp[r] + lane * 4);
  float4 z = ld4(Z0 + lane * 4), zn;
  for (int kb = 0; kb < NED; kb += 256) {
    const int k = kb + lane * 4;
    const bool more = (kb + 256) < NED;
    if (more) {
      #pragma unroll
      for (int r = 0; r < 3; ++r) an[r] = ntload4(mp[r] + k + 256);
      zn = ld4(Z0 + k + 256);
    }
    #pragma unroll
    for (int r = 0; r < 3; ++r) {
      ua[r] += a[r].x*z.x + a[r].y*z.y + a[r].z*z.z + a[r].w*z.w;
      sa[r] += a[r].x + a[r].y + a[r].z + a[r].w;
    }
    if (more) {
      #pragma unroll
      for (int r = 0; r < 3; ++r) a[r] = an[r];
      z = zn;
    }
  }
  #pragma unroll
  for (int r = 0; r < 3; ++r)
    #pragma unroll
    for (int m = 1; m < 64; m <<= 1) {
      ua[r] += __shfl_xor(ua[r], m, 64);
      sa[r] += __shfl_xor(sa[r], m, 64);
    }
  if (lane == 0) {
    float s1 = 0.f, s2 = 0.f, s3 = 0.f, s4 = 0.f, s5 = 0.f;
    #pragma unroll
    for (int r = 0; r < 3; ++r) {
      u[r0 + r] = ua[r]; s[r0 + r] = sa[r];
      s1 += ua[r]; s2 += sa[r];
      s3 += ua[r] * ua[r]; s4 += sa[r] * sa[r]; s5 += ua[r] * sa[r];
    }
    red[w * 5 + 0] = s1; red[w * 5 + 1] = s2; red[w * 5 + 2] = s3;
    red[w * 5 + 3] = s4; red[w * 5 + 4] = s5;
  }
  __syncthreads();
  if (tid < 5)
    atomicAdd(st5 + tid, red[tid] + red[5 + tid] + red[10 + tid] + red[15 + tid]);
}

// ==== K8: Z1 from (u,s) via collapsed BN. 48 blocks. ====
__global__ __launch_bounds__(256)
void k8_z1(const float* __restrict__ u, const float* __restrict__ s,
           const float* __restrict__ st5, const float* __restrict__ W1,
           const float* __restrict__ b1, const float* __restrict__ g,
           const float* __restrict__ beta, float* __restrict__ Z1) {
  const int e = blockIdx.x * 256 + threadIdx.x;
  const float invE = 1.f / (float)NED;
  const float Su = st5[0], Ss = st5[1], Suu = st5[2], Sss = st5[3], Sus = st5[4];
  const float uu = u[e], ssv = s[e];
  float best = -3.4e38f;
  #pragma unroll
  for (int c = 0; c < 16; ++c) {
    const float wc = W1[c], bc = b1[c];
    const float mean = (wc * Su + bc * Ss) * invE;
    const float ex2 = (wc * wc * Suu + 2.f * wc * bc * Sus + bc * bc * Sss) * invE;
    const float var = ex2 - mean * mean;
    const float sc = g[c] * rsqrtf(var + EPS_BN);
    const float sh = beta[c] - mean * sc;
    best = fmaxf(best, fmaf(wc * uu + bc * ssv, sc, sh));
  }
  Z1[e] = fmaxf(best, 0.f);
}

// ==== K9: he = B1 @ [Z0 Z1]. 512 blocks x 12 rows. ====
__global__ __launch_bounds__(256, 4)
void k9_b1pass(const float* __restrict__ B1, const float* __restrict__ Z0,
               const float* __restrict__ Z1, float* __restrict__ he) {
  const int lane = threadIdx.x & 63, w = threadIdx.x >> 6;
  const int r0 = blockIdx.x * 12 + w * 3;
  const float* mp[3];
  #pragma unroll
  for (int r = 0; r < 3; ++r) mp[r] = B1 + (size_t)(r0 + r) * NED;
  float uu[3] = {0,0,0}, vv[3] = {0,0,0};
  float4 a[3], an[3];
  #pragma unroll
  for (int r = 0; r < 3; ++r) a[r] = ntload4(mp[r] + lane * 4);
  float4 z = ld4(Z0 + lane * 4), y = ld4(Z1 + lane * 4), zn, yn;
  for (int kb = 0; kb < NED; kb += 256) {
    const int k = kb + lane * 4;
    const bool more = (kb + 256) < NED;
    if (more) {
      #pragma unroll
      for (int r = 0; r < 3; ++r) an[r] = ntload4(mp[r] + k + 256);
      zn = ld4(Z0 + k + 256); yn = ld4(Z1 + k + 256);
    }
    #pragma unroll
    for (int r = 0; r < 3; ++r) {
      uu[r] += a[r].x*z.x + a[r].y*z.y + a[r].z*z.z + a[r].w*z.w;
      vv[r] += a[r].x*y.x + a[r].y*y.y + a[r].z*y.z + a[r].w*y.w;
    }
    if (more) {
      #pragma unroll
      for (int r = 0; r < 3; ++r) a[r] = an[r];
      z = zn; y = yn;
    }
  }
  #pragma unroll
  for (int r = 0; r < 3; ++r)
    #pragma unroll
    for (int m = 1; m < 64; m <<= 1) {
      uu[r] += __shfl_xor(uu[r], m, 64);
      vv[r] += __shfl_xor(vv[r], m, 64);
    }
  if (lane == 0) {
    #pragma unroll
    for (int r = 0; r < 3; ++r) {
      he[(r0 + r) * 2]     = uu[r];
      he[(r0 + r) * 2 + 1] = vv[r];
    }
  }
}

// ==== K10: head partials. grid (8,64); 3 rows/thread, 192 j/chunk. ====
// Own kernel -> own register budget (h[3][34] = 102 VGPR live, no spill).
__global__ __launch_bounds__(256, 2)
void k10_head(const float* __restrict__ Hn, const float* __restrict__ he,
              const float* __restrict__ W1, const float* __restrict__ b1,
              const float* __restrict__ w2, float* __restrict__ pp) {
  const int t = threadIdx.x;
  const int nb = blockIdx.x;      // 8 bands of 768 rows
  const int jb = blockIdx.y;      // 64 chunks of 192 j
  int n[3];
  float h[3][34];
  float acc[3] = {0.f, 0.f, 0.f};
  #pragma unroll
  for (int i = 0; i < 3; ++i) {
    n[i] = nb * 768 + i * 256 + t;
    #pragma unroll
    for (int k = 0; k < 32; k += 4) {
      float4 v = ld4(Hn + (size_t)n[i] * 32 + k);
      h[i][k] = v.x; h[i][k+1] = v.y; h[i][k+2] = v.z; h[i][k+3] = v.w;
    }
    float2 e2 = *reinterpret_cast<const float2*>(he + n[i] * 2);
    h[i][32] = e2.x; h[i][33] = e2.y;
  }
  const int j0 = jb * 192;
  for (int j = j0; j < j0 + 192; ++j) {
    const float* wp = W1 + (size_t)j * 34;
    const float bj = b1[j], vj = w2[j];
    float s0 = bj, s1 = bj, s2 = bj;
    #pragma unroll
    for (int k = 0; k < 34; ++k) {
      const float wk = wp[k];
      s0 = fmaf(h[0][k], wk, s0);
      s1 = fmaf(h[1][k], wk, s1);
      s2 = fmaf(h[2][k], wk, s2);
    }
    acc[0] += fmaxf(s0, 0.f) * vj;
    acc[1] += fmaxf(s1, 0.f) * vj;
    acc[2] += fmaxf(s2, 0.f) * vj;
  }
  #pragma unroll
  for (int i = 0; i < 3; ++i) pp[(size_t)jb * NND + n[i]] = acc[i];
}

// ==== K11: final reduce + sigmoid. 24 blocks. ====
__global__ __launch_bounds__(256)
void k11_final(const float* __restrict__ pp, const float* __restrict__ b2,
               float* __restrict__ out) {
  const int i = blockIdx.x * 256 + threadIdx.x;
  float acc = 0.f;
  #pragma unroll
  for (int j = 0; j < 64; ++j) acc += pp[(size_t)j * NND + i];
  out[i] = 1.f / (1.f + expf(-(acc + b2[0])));
}

extern "C" void kernel_launch(void* const* d_in, const int* in_sizes, int n_in,
                              void* d_out, int out_size, void* d_ws, size_t ws_size,
                              hipStream_t stream) {
  const float* X_n  = (const float*)d_in[0];
  const float* X_e  = (const float*)d_in[1];
  const float* A    = (const float*)d_in[2];
  const float* L1   = (const float*)d_in[3];
  const float* B1   = (const float*)d_in[4];
  const float* gW0  = (const float*)d_in[5];
  const float* gb0  = (const float*)d_in[6];
  const float* gW1  = (const float*)d_in[7];
  const float* gb1  = (const float*)d_in[8];
  const float* tW0  = (const float*)d_in[9];
  const float* tb0  = (const float*)d_in[10];
  const float* bng0 = (const float*)d_in[11];
  const float* bnb0 = (const float*)d_in[12];
  const float* tW1  = (const float*)d_in[13];
  const float* tb1  = (const float*)d_in[14];
  const float* bng1 = (const float*)d_in[15];
  const float* bnb1 = (const float*)d_in[16];
  const float* fc1W = (const float*)d_in[17];
  const float* fc1b = (const float*)d_in[18];
  const float* fc2W = (const float*)d_in[19];
  const float* fc2b = (const float*)d_in[20];

  float* ws = (float*)d_ws;
  float* Hn = ws + HN_OFF;
  float* he = ws + HE_OFF;
  float* st = ws + ST_OFF;
  float* Y  = ws + Y_OFF;
  float* T0 = ws + T0_OFF;
  float* ZT = ws + ZT_OFF;
  float* ZC = ws + ZC_OFF;
  float* Z0 = ws + Z0_OFF;
  float* Z1 = ws + Z1_OFF;
  float* u  = ws + U_OFF;
  float* s  = ws + S_OFF;
  float* pp = ws + PP_OFF;
  float* out = (float*)d_out;

  k1_prep<<<72, 256, 0, stream>>>(X_n, X_e, gW0, tW0, tb0, Y, ZT, st);
  k2_gemm32<<<1024, 256, 0, stream>>>(A, Y, gb0, T0);
  k3_small<<<24, 256, 0, stream>>>(T0, gW1, Y);
  k2_gemm32<<<1024, 256, 0, stream>>>(A, Y, gb1, Hn);
  k5_l1gemm<<<1024, 256, 0, stream>>>(L1, ZT, ZC, st);
  k6_bnmax<<<48, 256, 0, stream>>>(ZC, st, bng0, bnb0, Z0);
  k7_uspass<<<1024, 256, 0, stream>>>(L1, Z0, u, s, st + 32);
  k8_z1<<<48, 256, 0, stream>>>(u, s, st + 32, tW1, tb1, bng1, bnb1, Z1);
  k9_b1pass<<<512, 256, 0, stream>>>(B1, Z0, Z1, he);
  k10_head<<<dim3(8, 64), 256, 0, stream>>>(Hn, he, fc1W, fc1b, fc2W, pp);
  k11_final<<<24, 256, 0, stream>>>(pp, fc2b, out);
}